// Round 2
// baseline (509.274 us; speedup 1.0000x reference)
//
#include <hip/hip_runtime.h>

// ---------------------------------------------------------------------------
// colorableGNN: 3x GCN(128->128) + FC(128->128) + FC(128->2) + mean-pool + softmax
// dtypes (per harness contract): float inputs fp32, indices int32, output fp32.
// Strategy: (A h)W == A(hW)  =>  per layer: Z = Ahat*H (sparse), H = relu(Z*W+b).
// Round 1: fp32 everywhere, correctness-first.
// ---------------------------------------------------------------------------

#define CH 128

// ---- init: zero counters --------------------------------------------------
__global__ void k_init(int* __restrict__ degi, int* __restrict__ fill,
                       float* __restrict__ sums, float* __restrict__ cnts,
                       int N, int G) {
    int i = blockIdx.x * blockDim.x + threadIdx.x;
    if (i < N) { degi[i] = 0; fill[i] = 0; }
    if (i < G) { sums[2 * i] = 0.f; sums[2 * i + 1] = 0.f; cnts[i] = 0.f; }
}

// ---- degree histogram over destinations -----------------------------------
__global__ void k_deg(const int* __restrict__ col, int* __restrict__ degi, int E) {
    int e = blockIdx.x * blockDim.x + threadIdx.x;
    if (e < E) atomicAdd(&degi[col[e]], 1);
}

__global__ void k_invs(const int* __restrict__ degi, float* __restrict__ invs, int N) {
    int i = blockIdx.x * blockDim.x + threadIdx.x;
    if (i < N) invs[i] = rsqrtf((float)degi[i] + 1.0f);
}

// ---- hierarchical exclusive scan (3 kernels) ------------------------------
__global__ void k_scan1(const int* __restrict__ degi, int* __restrict__ incl,
                        int* __restrict__ bsum, int N) {
    __shared__ int s[256];
    int t = threadIdx.x;
    int i = blockIdx.x * 256 + t;
    int v = (i < N) ? degi[i] : 0;
    s[t] = v;
    __syncthreads();
    for (int off = 1; off < 256; off <<= 1) {
        int u = (t >= off) ? s[t - off] : 0;
        __syncthreads();
        s[t] += u;
        __syncthreads();
    }
    if (i < N) incl[i] = s[t];
    if (t == 255) bsum[blockIdx.x] = s[255];
}

__global__ void k_scan2(const int* __restrict__ bsum, int* __restrict__ bofs, int NB) {
    __shared__ int s[256];
    int t = threadIdx.x;
    int v = (t < NB) ? bsum[t] : 0;
    s[t] = v;
    __syncthreads();
    for (int off = 1; off < 256; off <<= 1) {
        int u = (t >= off) ? s[t - off] : 0;
        __syncthreads();
        s[t] += u;
        __syncthreads();
    }
    if (t < NB) bofs[t] = s[t] - v;  // exclusive
}

__global__ void k_scan3(const int* __restrict__ degi, const int* __restrict__ bofs,
                        int* __restrict__ indptr, int N) {
    int i = blockIdx.x * 256 + threadIdx.x;
    if (i < N) {
        int incl = indptr[i];
        int base = bofs[blockIdx.x];
        indptr[i] = incl - degi[i] + base;        // exclusive
        if (i == N - 1) indptr[N] = incl + base;  // total = E
    }
}

// ---- CSR fill -------------------------------------------------------------
__global__ void k_fill(const int* __restrict__ row, const int* __restrict__ col,
                       const int* __restrict__ indptr, int* __restrict__ fill,
                       const float* __restrict__ invs, int* __restrict__ esrc,
                       float* __restrict__ enorm, int E) {
    int e = blockIdx.x * blockDim.x + threadIdx.x;
    if (e < E) {
        int r = row[e], c = col[e];
        int p = indptr[c] + atomicAdd(&fill[c], 1);
        esrc[p] = r;
        enorm[p] = invs[r] * invs[c];
    }
}

// ---- aggregation: Z[n] = invs[n]^2 * H[n] + sum_e norm * H[src] -----------
// one wave per node, lane handles channels (2*lane, 2*lane+1)
__global__ __launch_bounds__(256) void k_agg(const float* __restrict__ Hsrc,
                                             const int* __restrict__ esrc,
                                             const float* __restrict__ enorm,
                                             const int* __restrict__ indptr,
                                             const float* __restrict__ invs,
                                             float* __restrict__ Z, int N) {
    int node = blockIdx.x * 4 + (threadIdx.x >> 6);
    if (node >= N) return;
    int lane = threadIdx.x & 63;

    const float2* H2 = reinterpret_cast<const float2*>(Hsrc);

    float sn = invs[node];
    float sn2 = sn * sn;
    float2 h = H2[node * 64 + lane];
    float ax = sn2 * h.x, ay = sn2 * h.y;

    int p = indptr[node];
    int p1 = indptr[node + 1];
    for (; p + 4 <= p1; p += 4) {
        int s0 = esrc[p], s1 = esrc[p + 1], s2 = esrc[p + 2], s3 = esrc[p + 3];
        float w0 = enorm[p], w1 = enorm[p + 1], w2 = enorm[p + 2], w3 = enorm[p + 3];
        float2 g0 = H2[s0 * 64 + lane];
        float2 g1 = H2[s1 * 64 + lane];
        float2 g2 = H2[s2 * 64 + lane];
        float2 g3 = H2[s3 * 64 + lane];
        ax += w0 * g0.x + w1 * g1.x + w2 * g2.x + w3 * g3.x;
        ay += w0 * g0.y + w1 * g1.y + w2 * g2.y + w3 * g3.y;
    }
    for (; p < p1; ++p) {
        int s = esrc[p];
        float wv = enorm[p];
        float2 g = H2[s * 64 + lane];
        ax += wv * g.x;
        ay += wv * g.y;
    }
    reinterpret_cast<float2*>(Z)[node * 64 + lane] = make_float2(ax, ay);
}

// ---- fused GEMM: Out[N,128] = relu?(In[N,128] @ W[128,128] + b) -----------
// block 256, 64-row tile, K chunks of 32 in LDS, 4 rows x 8 cols per thread.
__global__ __launch_bounds__(256) void k_gemm(const float* __restrict__ In,
                                              const float* __restrict__ W,
                                              const float* __restrict__ B,
                                              float* __restrict__ Out, int N,
                                              int doRelu) {
    __shared__ float Ws[32 * 128];   // 16 KB
    __shared__ float Zs[64 * 33];    // 8.4 KB (stride 33)
    const int tid = threadIdx.x;
    const int cg = tid >> 4;   // 0..15 -> cols j0 = cg*8
    const int rg = tid & 15;   // 0..15 -> rows rg*4..rg*4+3
    const int j0 = cg * 8;
    const int row0 = blockIdx.x * 64;

    float acc[4][8];
#pragma unroll
    for (int i = 0; i < 4; i++)
#pragma unroll
        for (int j = 0; j < 8; j++) acc[i][j] = 0.f;

    for (int kc = 0; kc < 128; kc += 32) {
        // stage W chunk (32x128 fp32 = 1024 float4; 4 per thread, coalesced)
#pragma unroll
        for (int q = 0; q < 4; ++q) {
            int pidx = tid * 4 + q;        // 0..1023 float4 slots
            int k = pidx >> 5;             // 0..31
            int j4 = (pidx & 31) * 4;      // 0..124
            float4 v = *reinterpret_cast<const float4*>(W + (kc + k) * CH + j4);
            float* wp = &Ws[k * CH + j4];
            wp[0] = v.x; wp[1] = v.y; wp[2] = v.z; wp[3] = v.w;
        }
        // stage Z chunk (64 rows x 32 k = 512 float4 slots)
#pragma unroll
        for (int q2 = 0; q2 < 2; ++q2) {
            int q = tid + q2 * 256;
            int r = q >> 3;
            int kq = q & 7;
            int row = row0 + r;
            float4 v = make_float4(0.f, 0.f, 0.f, 0.f);
            if (row < N)
                v = *reinterpret_cast<const float4*>(In + row * CH + kc + kq * 4);
            float* zp = &Zs[r * 33 + kq * 4];
            zp[0] = v.x; zp[1] = v.y; zp[2] = v.z; zp[3] = v.w;
        }
        __syncthreads();
#pragma unroll
        for (int kk = 0; kk < 32; ++kk) {
            float zv[4];
#pragma unroll
            for (int i = 0; i < 4; i++) zv[i] = Zs[(rg * 4 + i) * 33 + kk];
            float4 wa = *reinterpret_cast<const float4*>(&Ws[kk * CH + j0]);
            float4 wb = *reinterpret_cast<const float4*>(&Ws[kk * CH + j0 + 4]);
            float wv[8] = {wa.x, wa.y, wa.z, wa.w, wb.x, wb.y, wb.z, wb.w};
#pragma unroll
            for (int i = 0; i < 4; i++)
#pragma unroll
                for (int j = 0; j < 8; j++) acc[i][j] += zv[i] * wv[j];
        }
        __syncthreads();
    }

    float bj[8];
#pragma unroll
    for (int j = 0; j < 8; j++) bj[j] = B[j0 + j];

#pragma unroll
    for (int i = 0; i < 4; i++) {
        int row = row0 + rg * 4 + i;
        if (row < N) {
            float o[8];
#pragma unroll
            for (int j = 0; j < 8; j++) {
                float v = acc[i][j] + bj[j];
                o[j] = doRelu ? fmaxf(v, 0.f) : v;
            }
            float4* dst = reinterpret_cast<float4*>(Out + row * CH + j0);
            dst[0] = make_float4(o[0], o[1], o[2], o[3]);
            dst[1] = make_float4(o[4], o[5], o[6], o[7]);
        }
    }
}

// ---- FC2: logits[n,2] = H[n,:] @ fcW2[128,2] + fcb2 -----------------------
__global__ __launch_bounds__(256) void k_fc2(const float* __restrict__ H,
                                             const float* __restrict__ W2,
                                             const float* __restrict__ B2,
                                             float* __restrict__ logits, int N) {
    int node = blockIdx.x * 4 + (threadIdx.x >> 6);
    if (node >= N) return;
    int lane = threadIdx.x & 63;
    float2 h = *reinterpret_cast<const float2*>(H + node * CH + lane * 2);
    // fcW2 row-major [c][o]; lane covers c = 2*lane, 2*lane+1 -> 4 consecutive floats
    float4 w = *reinterpret_cast<const float4*>(W2 + lane * 4);
    // w.x = W2[2l][0], w.y = W2[2l][1], w.z = W2[2l+1][0], w.w = W2[2l+1][1]
    float d0 = h.x * w.x + h.y * w.z;
    float d1 = h.x * w.y + h.y * w.w;
#pragma unroll
    for (int off = 32; off > 0; off >>= 1) {
        d0 += __shfl_down(d0, off, 64);
        d1 += __shfl_down(d1, off, 64);
    }
    if (lane == 0) {
        logits[node * 2] = d0 + B2[0];
        logits[node * 2 + 1] = d1 + B2[1];
    }
}

// ---- per-graph mean pool (batch sorted -> few graphs per block) -----------
__global__ __launch_bounds__(256) void k_pool(const float* __restrict__ logits,
                                              const int* __restrict__ batch,
                                              float* __restrict__ sums,
                                              float* __restrict__ cnts, int N, int G) {
    __shared__ float ls[192];  // [0..63]=sum0 [64..127]=sum1 [128..191]=cnt
    int t = threadIdx.x;
    if (t < 192) ls[t] = 0.f;
    __syncthreads();
    int n = blockIdx.x * 256 + t;
    if (n < N) {
        int g = batch[n];
        atomicAdd(&ls[g], logits[2 * n]);
        atomicAdd(&ls[64 + g], logits[2 * n + 1]);
        atomicAdd(&ls[128 + g], 1.0f);
    }
    __syncthreads();
    if (t < G) {
        float c = ls[128 + t];
        if (c != 0.f) {
            atomicAdd(&sums[2 * t], ls[t]);
            atomicAdd(&sums[2 * t + 1], ls[64 + t]);
            atomicAdd(&cnts[t], c);
        }
    }
}

__global__ void k_softmax(const float* __restrict__ sums, const float* __restrict__ cnts,
                          float* __restrict__ out, int G) {
    int g = blockIdx.x * blockDim.x + threadIdx.x;
    if (g < G) {
        float c = fmaxf(cnts[g], 1.0f);
        float p0 = sums[2 * g] / c;
        float p1 = sums[2 * g + 1] / c;
        float m = fmaxf(p0, p1);
        float e0 = expf(p0 - m), e1 = expf(p1 - m);
        float inv = 1.f / (e0 + e1);
        out[2 * g] = e0 * inv;
        out[2 * g + 1] = e1 * inv;
    }
}

// ---------------------------------------------------------------------------
extern "C" void kernel_launch(void* const* d_in, const int* in_sizes, int n_in,
                              void* d_out, int out_size, void* d_ws, size_t ws_size,
                              hipStream_t stream) {
    const float* X   = (const float*)d_in[0];
    const int* EI    = (const int*)d_in[1];
    const int* BATCH = (const int*)d_in[2];
    const float* W1  = (const float*)d_in[3];
    const float* B1  = (const float*)d_in[4];
    const float* W2  = (const float*)d_in[5];
    const float* B2  = (const float*)d_in[6];
    const float* W3  = (const float*)d_in[7];
    const float* B3  = (const float*)d_in[8];
    const float* FW1 = (const float*)d_in[9];
    const float* FB1 = (const float*)d_in[10];
    const float* FW2 = (const float*)d_in[11];
    const float* FB2 = (const float*)d_in[12];

    const int N = in_sizes[0] / CH;
    const int E = in_sizes[1] / 2;
    const int G = out_size / 2;
    const int* rowp = EI;
    const int* colp = EI + E;

    char* w = (char*)d_ws;
    auto alloc = [&](size_t bytes) -> char* {
        char* p = w;
        w += (bytes + 255) & ~(size_t)255;
        return p;
    };
    float* H      = (float*)alloc((size_t)N * CH * 4);
    float* Z      = (float*)alloc((size_t)N * CH * 4);
    int*   degi   = (int*)alloc((size_t)N * 4);
    float* invs   = (float*)alloc((size_t)N * 4);
    int*   indptr = (int*)alloc((size_t)(N + 1) * 4);
    int*   fillc  = (int*)alloc((size_t)N * 4);
    int*   esrc   = (int*)alloc((size_t)E * 4);
    float* enorm  = (float*)alloc((size_t)E * 4);
    int*   bsum   = (int*)alloc(1024 * 4);
    int*   bofs   = (int*)alloc(1024 * 4);
    float* sums   = (float*)alloc((size_t)G * 2 * 4);
    float* cnts   = (float*)alloc((size_t)G * 4);
    float* logits = (float*)alloc((size_t)N * 2 * 4);

    const int nb256  = (N + 255) / 256;
    const int nbE    = (E + 255) / 256;
    const int nbAgg  = (N + 3) / 4;
    const int nbGemm = (N + 63) / 64;

    k_init<<<nb256, 256, 0, stream>>>(degi, fillc, sums, cnts, N, G);
    k_deg<<<nbE, 256, 0, stream>>>(colp, degi, E);
    k_invs<<<nb256, 256, 0, stream>>>(degi, invs, N);
    k_scan1<<<nb256, 256, 0, stream>>>(degi, indptr, bsum, N);
    k_scan2<<<1, 256, 0, stream>>>(bsum, bofs, nb256);
    k_scan3<<<nb256, 256, 0, stream>>>(degi, bofs, indptr, N);
    k_fill<<<nbE, 256, 0, stream>>>(rowp, colp, indptr, fillc, invs, esrc, enorm, E);

    // layer 1
    k_agg<<<nbAgg, 256, 0, stream>>>(X, esrc, enorm, indptr, invs, Z, N);
    k_gemm<<<nbGemm, 256, 0, stream>>>(Z, W1, B1, H, N, 1);
    // layer 2
    k_agg<<<nbAgg, 256, 0, stream>>>(H, esrc, enorm, indptr, invs, Z, N);
    k_gemm<<<nbGemm, 256, 0, stream>>>(Z, W2, B2, H, N, 1);
    // layer 3
    k_agg<<<nbAgg, 256, 0, stream>>>(H, esrc, enorm, indptr, invs, Z, N);
    k_gemm<<<nbGemm, 256, 0, stream>>>(Z, W3, B3, H, N, 1);
    // FC1
    k_gemm<<<nbGemm, 256, 0, stream>>>(H, FW1, FB1, Z, N, 1);
    // FC2 + pool + softmax
    k_fc2<<<nbAgg, 256, 0, stream>>>(Z, FW2, FB2, logits, N);
    k_pool<<<nb256, 256, 0, stream>>>(logits, BATCH, sums, cnts, N, G);
    k_softmax<<<(G + 63) / 64, 64, 0, stream>>>(sums, cnts, (float*)d_out, G);
}

// Round 3
// 369.175 us; speedup vs baseline: 1.3795x; 1.3795x over previous
//
#include <hip/hip_runtime.h>

// ---------------------------------------------------------------------------
// colorableGNN: 3x GCN(128->128) + FC(128->128) + FC(128->2) + mean-pool + softmax
// R2: activations stored bf16 (halves the XCD-L2 re-fetch in the gather, which
// rocprof showed at 189MB/dispatch = 7.4x of H), GEMMs via bf16 MFMA with
// weight hi/lo split (systematic weight rounding would NOT pool away; hi+lo
// gives ~fp32 weights at 2 MFMAs/tile). fp32 accumulate everywhere.
// ---------------------------------------------------------------------------

#define CH 128

typedef unsigned short ushortT;
typedef unsigned int uintT;
typedef __attribute__((ext_vector_type(8))) short short8;
typedef __attribute__((ext_vector_type(4))) float floatx4;

__device__ __forceinline__ float bf2f(uintT u) {
    return __uint_as_float(u << 16);
}
__device__ __forceinline__ ushortT f2bf(float f) {
    uintT x = __float_as_uint(f);
    return (ushortT)((x + 0x7fffu + ((x >> 16) & 1u)) >> 16);
}

// ---- init: zero counters --------------------------------------------------
__global__ void k_init(int* __restrict__ degi, int* __restrict__ fill,
                       float* __restrict__ sums, float* __restrict__ cnts,
                       int N, int G) {
    int i = blockIdx.x * blockDim.x + threadIdx.x;
    if (i < N) { degi[i] = 0; fill[i] = 0; }
    if (i < G) { sums[2 * i] = 0.f; sums[2 * i + 1] = 0.f; cnts[i] = 0.f; }
}

__global__ void k_deg(const int* __restrict__ col, int* __restrict__ degi, int E) {
    int e = blockIdx.x * blockDim.x + threadIdx.x;
    if (e < E) atomicAdd(&degi[col[e]], 1);
}

// ---- scan1 also produces invs (fused, saves a launch) ---------------------
__global__ void k_scan1(const int* __restrict__ degi, int* __restrict__ incl,
                        int* __restrict__ bsum, float* __restrict__ invs, int N) {
    __shared__ int s[256];
    int t = threadIdx.x;
    int i = blockIdx.x * 256 + t;
    int v = (i < N) ? degi[i] : 0;
    if (i < N) invs[i] = rsqrtf((float)v + 1.0f);
    s[t] = v;
    __syncthreads();
    for (int off = 1; off < 256; off <<= 1) {
        int u = (t >= off) ? s[t - off] : 0;
        __syncthreads();
        s[t] += u;
        __syncthreads();
    }
    if (i < N) incl[i] = s[t];
    if (t == 255) bsum[blockIdx.x] = s[255];
}

__global__ void k_scan2(const int* __restrict__ bsum, int* __restrict__ bofs, int NB) {
    __shared__ int s[256];
    int t = threadIdx.x;
    int v = (t < NB) ? bsum[t] : 0;
    s[t] = v;
    __syncthreads();
    for (int off = 1; off < 256; off <<= 1) {
        int u = (t >= off) ? s[t - off] : 0;
        __syncthreads();
        s[t] += u;
        __syncthreads();
    }
    if (t < NB) bofs[t] = s[t] - v;  // exclusive
}

__global__ void k_scan3(const int* __restrict__ degi, const int* __restrict__ bofs,
                        int* __restrict__ indptr, int N) {
    int i = blockIdx.x * 256 + threadIdx.x;
    if (i < N) {
        int incl = indptr[i];
        int base = bofs[blockIdx.x];
        indptr[i] = incl - degi[i] + base;
        if (i == N - 1) indptr[N] = incl + base;
    }
}

__global__ void k_fill(const int* __restrict__ row, const int* __restrict__ col,
                       const int* __restrict__ indptr, int* __restrict__ fill,
                       const float* __restrict__ invs, int* __restrict__ esrc,
                       float* __restrict__ enorm, int E) {
    int e = blockIdx.x * blockDim.x + threadIdx.x;
    if (e < E) {
        int r = row[e], c = col[e];
        int p = indptr[c] + atomicAdd(&fill[c], 1);
        esrc[p] = r;
        enorm[p] = invs[r] * invs[c];
    }
}

// ---- X fp32 -> bf16 -------------------------------------------------------
__global__ void k_tobf16(const float* __restrict__ X, ushortT* __restrict__ Xb, int total4) {
    int i = blockIdx.x * blockDim.x + threadIdx.x;
    if (i < total4) {
        float4 v = reinterpret_cast<const float4*>(X)[i];
        uint2 o;
        o.x = (uintT)f2bf(v.x) | ((uintT)f2bf(v.y) << 16);
        o.y = (uintT)f2bf(v.z) | ((uintT)f2bf(v.w) << 16);
        reinterpret_cast<uint2*>(Xb)[i] = o;
    }
}

// ---- weight prep: W[k][n] fp32 -> Wt_hi/Wt_lo[n][k] bf16 (transposed) -----
// 4 matrices of 128x128. hi=bf16(w), lo=bf16(w-hi): ~fp32 effective weights.
__global__ void k_prepw(const float* __restrict__ w0, const float* __restrict__ w1,
                        const float* __restrict__ w2, const float* __restrict__ w3,
                        ushortT* __restrict__ Whi, ushortT* __restrict__ Wlo) {
    int idx = blockIdx.x * 256 + threadIdx.x;  // 0..65535
    int m = idx >> 14;
    int r = idx & 16383;
    int n = r >> 7;
    int k = r & 127;
    const float* W = (m == 0) ? w0 : (m == 1) ? w1 : (m == 2) ? w2 : w3;
    float w = W[k * CH + n];
    ushortT hi = f2bf(w);
    float lo = w - bf2f(hi);
    Whi[m * 16384 + n * CH + k] = hi;
    Wlo[m * 16384 + n * CH + k] = f2bf(lo);
}

// ---- aggregation (bf16 in/out, fp32 accumulate) ---------------------------
__global__ __launch_bounds__(256) void k_agg(const ushortT* __restrict__ Hb,
                                             const int* __restrict__ esrc,
                                             const float* __restrict__ enorm,
                                             const int* __restrict__ indptr,
                                             const float* __restrict__ invs,
                                             ushortT* __restrict__ Zb, int N) {
    int node = blockIdx.x * 4 + (threadIdx.x >> 6);
    if (node >= N) return;
    int lane = threadIdx.x & 63;

    const uintT* H32 = reinterpret_cast<const uintT*>(Hb);

    float sn = invs[node];
    float sn2 = sn * sn;
    uintT hu = H32[(size_t)node * 64 + lane];
    float ax = sn2 * bf2f(hu & 0xffffu);
    float ay = sn2 * bf2f(hu >> 16);

    int p = indptr[node];
    int p1 = indptr[node + 1];
    for (; p + 4 <= p1; p += 4) {
        int s0 = esrc[p], s1 = esrc[p + 1], s2 = esrc[p + 2], s3 = esrc[p + 3];
        float w0 = enorm[p], w1 = enorm[p + 1], w2 = enorm[p + 2], w3 = enorm[p + 3];
        uintT g0 = H32[(size_t)s0 * 64 + lane];
        uintT g1 = H32[(size_t)s1 * 64 + lane];
        uintT g2 = H32[(size_t)s2 * 64 + lane];
        uintT g3 = H32[(size_t)s3 * 64 + lane];
        ax += w0 * bf2f(g0 & 0xffffu) + w1 * bf2f(g1 & 0xffffu) +
              w2 * bf2f(g2 & 0xffffu) + w3 * bf2f(g3 & 0xffffu);
        ay += w0 * bf2f(g0 >> 16) + w1 * bf2f(g1 >> 16) +
              w2 * bf2f(g2 >> 16) + w3 * bf2f(g3 >> 16);
    }
    for (; p < p1; ++p) {
        int s = esrc[p];
        float wv = enorm[p];
        uintT g = H32[(size_t)s * 64 + lane];
        ax += wv * bf2f(g & 0xffffu);
        ay += wv * bf2f(g >> 16);
    }
    uintT o = (uintT)f2bf(ax) | ((uintT)f2bf(ay) << 16);
    reinterpret_cast<uintT*>(Zb)[(size_t)node * 64 + lane] = o;
}

// ---- MFMA GEMM: Out[N,128] = relu?(Z[N,128] @ (Whi+Wlo) + b), all bf16 ----
// Block 256 = 4 waves, tile 128 rows x 128 cols; wave quadrant 64x64 (4x4
// tiles of 16x16x32). K chunked at 32 (4 steps). LDS strides: 40 elems for
// A/W chunks (80B = 20 dwords -> 2-way b128 conflicts, free), 132 for C.
#define SA 40
#define SC 132
__global__ __launch_bounds__(256) void k_gemm(const ushortT* __restrict__ Zg,
                                              const ushortT* __restrict__ Whi,
                                              const ushortT* __restrict__ Wlo,
                                              const float* __restrict__ Bias,
                                              ushortT* __restrict__ Out, int N,
                                              int doRelu) {
    __shared__ ushortT As[128 * SA];
    __shared__ ushortT Hs[128 * SA];
    __shared__ ushortT Ls[128 * SA];
    __shared__ ushortT Cs[128 * SC];

    const int tid = threadIdx.x;
    const int wave = tid >> 6, lane = tid & 63;
    const int quad = lane >> 4, l15 = lane & 15;
    const int mBase = (wave >> 1) * 64, nBase = (wave & 1) * 64;
    const int row0 = blockIdx.x * 128;
    const int r = tid >> 1, half = tid & 1;  // staging role

    floatx4 acc[4][4];
    const floatx4 zero4 = {0.f, 0.f, 0.f, 0.f};
#pragma unroll
    for (int i = 0; i < 4; i++)
#pragma unroll
        for (int j = 0; j < 4; j++) acc[i][j] = zero4;

    for (int ks = 0; ks < 4; ++ks) {
        // stage A chunk (128 rows x 32 k) and both W chunks
        {
            int grow = row0 + r;
            uint4 av0 = {0, 0, 0, 0}, av1 = {0, 0, 0, 0};
            if (grow < N) {
                const uint4* s = reinterpret_cast<const uint4*>(
                    Zg + (size_t)grow * CH + ks * 32 + half * 16);
                av0 = s[0]; av1 = s[1];
            }
            uint4* d = reinterpret_cast<uint4*>(&As[r * SA + half * 16]);
            d[0] = av0; d[1] = av1;
            const uint4* sh = reinterpret_cast<const uint4*>(Whi + r * CH + ks * 32 + half * 16);
            uint4* dh = reinterpret_cast<uint4*>(&Hs[r * SA + half * 16]);
            dh[0] = sh[0]; dh[1] = sh[1];
            const uint4* sl = reinterpret_cast<const uint4*>(Wlo + r * CH + ks * 32 + half * 16);
            uint4* dl = reinterpret_cast<uint4*>(&Ls[r * SA + half * 16]);
            dl[0] = sl[0]; dl[1] = sl[1];
        }
        __syncthreads();

        short8 af[4], hf[4], lf[4];
#pragma unroll
        for (int mt = 0; mt < 4; ++mt)
            af[mt] = *reinterpret_cast<const short8*>(&As[(mBase + mt * 16 + l15) * SA + quad * 8]);
#pragma unroll
        for (int nt = 0; nt < 4; ++nt) {
            hf[nt] = *reinterpret_cast<const short8*>(&Hs[(nBase + nt * 16 + l15) * SA + quad * 8]);
            lf[nt] = *reinterpret_cast<const short8*>(&Ls[(nBase + nt * 16 + l15) * SA + quad * 8]);
        }
#pragma unroll
        for (int mt = 0; mt < 4; ++mt)
#pragma unroll
            for (int nt = 0; nt < 4; ++nt) {
                acc[mt][nt] = __builtin_amdgcn_mfma_f32_16x16x32_bf16(af[mt], hf[nt], acc[mt][nt], 0, 0, 0);
                acc[mt][nt] = __builtin_amdgcn_mfma_f32_16x16x32_bf16(af[mt], lf[nt], acc[mt][nt], 0, 0, 0);
            }
        __syncthreads();
    }

    // epilogue: bias + relu, repack via LDS for coalesced bf16 row stores
    float bb[4];
#pragma unroll
    for (int nt = 0; nt < 4; ++nt) bb[nt] = Bias[nBase + nt * 16 + l15];

#pragma unroll
    for (int mt = 0; mt < 4; ++mt)
#pragma unroll
        for (int nt = 0; nt < 4; ++nt)
#pragma unroll
            for (int r4 = 0; r4 < 4; ++r4) {
                int lrow = mBase + mt * 16 + quad * 4 + r4;
                float v = acc[mt][nt][r4] + bb[nt];
                if (doRelu) v = fmaxf(v, 0.f);
                Cs[lrow * SC + nBase + nt * 16 + l15] = f2bf(v);
            }
    __syncthreads();
    {
        int grow = row0 + r;
        if (grow < N) {
            const uint2* s = reinterpret_cast<const uint2*>(&Cs[r * SC + half * 64]);
            uint4* dst = reinterpret_cast<uint4*>(Out + (size_t)grow * CH + half * 64);
#pragma unroll
            for (int q = 0; q < 8; ++q) {
                uint2 a = s[2 * q], b = s[2 * q + 1];
                uint4 o = {a.x, a.y, b.x, b.y};
                dst[q] = o;
            }
        }
    }
}

// ---- FC2: logits[n,2] = H[n,:] @ fcW2[128,2] + fcb2 (H bf16) --------------
__global__ __launch_bounds__(256) void k_fc2(const ushortT* __restrict__ H,
                                             const float* __restrict__ W2,
                                             const float* __restrict__ B2,
                                             float* __restrict__ logits, int N) {
    int node = blockIdx.x * 4 + (threadIdx.x >> 6);
    if (node >= N) return;
    int lane = threadIdx.x & 63;
    uintT hu = reinterpret_cast<const uintT*>(H)[(size_t)node * 64 + lane];
    float hx = bf2f(hu & 0xffffu), hy = bf2f(hu >> 16);
    float4 w = *reinterpret_cast<const float4*>(W2 + lane * 4);
    float d0 = hx * w.x + hy * w.z;
    float d1 = hx * w.y + hy * w.w;
#pragma unroll
    for (int off = 32; off > 0; off >>= 1) {
        d0 += __shfl_down(d0, off, 64);
        d1 += __shfl_down(d1, off, 64);
    }
    if (lane == 0) {
        logits[node * 2] = d0 + B2[0];
        logits[node * 2 + 1] = d1 + B2[1];
    }
}

__global__ __launch_bounds__(256) void k_pool(const float* __restrict__ logits,
                                              const int* __restrict__ batch,
                                              float* __restrict__ sums,
                                              float* __restrict__ cnts, int N, int G) {
    __shared__ float ls[192];
    int t = threadIdx.x;
    if (t < 192) ls[t] = 0.f;
    __syncthreads();
    int n = blockIdx.x * 256 + t;
    if (n < N) {
        int g = batch[n];
        atomicAdd(&ls[g], logits[2 * n]);
        atomicAdd(&ls[64 + g], logits[2 * n + 1]);
        atomicAdd(&ls[128 + g], 1.0f);
    }
    __syncthreads();
    if (t < G) {
        float c = ls[128 + t];
        if (c != 0.f) {
            atomicAdd(&sums[2 * t], ls[t]);
            atomicAdd(&sums[2 * t + 1], ls[64 + t]);
            atomicAdd(&cnts[t], c);
        }
    }
}

__global__ void k_softmax(const float* __restrict__ sums, const float* __restrict__ cnts,
                          float* __restrict__ out, int G) {
    int g = blockIdx.x * blockDim.x + threadIdx.x;
    if (g < G) {
        float c = fmaxf(cnts[g], 1.0f);
        float p0 = sums[2 * g] / c;
        float p1 = sums[2 * g + 1] / c;
        float m = fmaxf(p0, p1);
        float e0 = expf(p0 - m), e1 = expf(p1 - m);
        float inv = 1.f / (e0 + e1);
        out[2 * g] = e0 * inv;
        out[2 * g + 1] = e1 * inv;
    }
}

// ---------------------------------------------------------------------------
extern "C" void kernel_launch(void* const* d_in, const int* in_sizes, int n_in,
                              void* d_out, int out_size, void* d_ws, size_t ws_size,
                              hipStream_t stream) {
    const float* X   = (const float*)d_in[0];
    const int* EI    = (const int*)d_in[1];
    const int* BATCH = (const int*)d_in[2];
    const float* W1  = (const float*)d_in[3];
    const float* B1  = (const float*)d_in[4];
    const float* W2  = (const float*)d_in[5];
    const float* B2  = (const float*)d_in[6];
    const float* W3  = (const float*)d_in[7];
    const float* B3  = (const float*)d_in[8];
    const float* FW1 = (const float*)d_in[9];
    const float* FB1 = (const float*)d_in[10];
    const float* FW2 = (const float*)d_in[11];
    const float* FB2 = (const float*)d_in[12];

    const int N = in_sizes[0] / CH;
    const int E = in_sizes[1] / 2;
    const int G = out_size / 2;
    const int* rowp = EI;
    const int* colp = EI + E;

    char* w = (char*)d_ws;
    auto alloc = [&](size_t bytes) -> char* {
        char* p = w;
        w += (bytes + 255) & ~(size_t)255;
        return p;
    };
    ushortT* Hb    = (ushortT*)alloc((size_t)N * CH * 2);
    ushortT* Zb    = (ushortT*)alloc((size_t)N * CH * 2);
    ushortT* Xb    = (ushortT*)alloc((size_t)N * CH * 2);
    ushortT* WhiA  = (ushortT*)alloc((size_t)4 * 16384 * 2);
    ushortT* WloA  = (ushortT*)alloc((size_t)4 * 16384 * 2);
    int*   degi    = (int*)alloc((size_t)N * 4);
    float* invs    = (float*)alloc((size_t)N * 4);
    int*   indptr  = (int*)alloc((size_t)(N + 1) * 4);
    int*   fillc   = (int*)alloc((size_t)N * 4);
    int*   esrc    = (int*)alloc((size_t)E * 4);
    float* enorm   = (float*)alloc((size_t)E * 4);
    int*   bsum    = (int*)alloc(1024 * 4);
    int*   bofs    = (int*)alloc(1024 * 4);
    float* sums    = (float*)alloc((size_t)G * 2 * 4);
    float* cnts    = (float*)alloc((size_t)G * 4);
    float* logits  = (float*)alloc((size_t)N * 2 * 4);

    const int nb256  = (N + 255) / 256;
    const int nbE    = (E + 255) / 256;
    const int nbAgg  = (N + 3) / 4;
    const int nbGemm = (N + 127) / 128;

    k_init<<<nb256, 256, 0, stream>>>(degi, fillc, sums, cnts, N, G);
    k_deg<<<nbE, 256, 0, stream>>>(colp, degi, E);
    k_scan1<<<nb256, 256, 0, stream>>>(degi, indptr, bsum, invs, N);
    k_scan2<<<1, 256, 0, stream>>>(bsum, bofs, nb256);
    k_scan3<<<nb256, 256, 0, stream>>>(degi, bofs, indptr, N);
    k_fill<<<nbE, 256, 0, stream>>>(rowp, colp, indptr, fillc, invs, esrc, enorm, E);
    k_tobf16<<<(N * CH / 4 + 255) / 256, 256, 0, stream>>>(X, Xb, N * CH / 4);
    k_prepw<<<256, 256, 0, stream>>>(W1, W2, W3, FW1, WhiA, WloA);

    // layer 1
    k_agg<<<nbAgg, 256, 0, stream>>>(Xb, esrc, enorm, indptr, invs, Zb, N);
    k_gemm<<<nbGemm, 256, 0, stream>>>(Zb, WhiA, WloA, B1, Hb, N, 1);
    // layer 2
    k_agg<<<nbAgg, 256, 0, stream>>>(Hb, esrc, enorm, indptr, invs, Zb, N);
    k_gemm<<<nbGemm, 256, 0, stream>>>(Zb, WhiA + 16384, WloA + 16384, B2, Hb, N, 1);
    // layer 3
    k_agg<<<nbAgg, 256, 0, stream>>>(Hb, esrc, enorm, indptr, invs, Zb, N);
    k_gemm<<<nbGemm, 256, 0, stream>>>(Zb, WhiA + 2 * 16384, WloA + 2 * 16384, B3, Hb, N, 1);
    // FC1
    k_gemm<<<nbGemm, 256, 0, stream>>>(Hb, WhiA + 3 * 16384, WloA + 3 * 16384, FB1, Zb, N, 1);
    // FC2 + pool + softmax
    k_fc2<<<nbAgg, 256, 0, stream>>>(Zb, FW2, FB2, logits, N);
    k_pool<<<nb256, 256, 0, stream>>>(logits, BATCH, sums, cnts, N, G);
    k_softmax<<<(G + 63) / 64, 64, 0, stream>>>(sums, cnts, (float*)d_out, G);
}

// Round 4
// 358.261 us; speedup vs baseline: 1.4215x; 1.0305x over previous
//
#include <hip/hip_runtime.h>

// ---------------------------------------------------------------------------
// colorableGNN: 3x GCN(128->128) + FC(128->128) + FC(128->2) + mean-pool + softmax
// R3: pack CSR edge record into one 8B store (R2 rocprof: k_fill WRITE_SIZE
// 83MB for 6.4MB payload = 2 dirty lines/edge), fuse small kernels, widen
// agg gather to 8 outstanding loads. Activations bf16, GEMM = MFMA with
// weight hi/lo split (~fp32 weights), fp32 accumulate.
// ---------------------------------------------------------------------------

#define CH 128

typedef unsigned short ushortT;
typedef unsigned int uintT;
typedef __attribute__((ext_vector_type(8))) short short8;
typedef __attribute__((ext_vector_type(4))) float floatx4;

__device__ __forceinline__ float bf2f(uintT u) {
    return __uint_as_float(u << 16);
}
__device__ __forceinline__ ushortT f2bf(float f) {
    uintT x = __float_as_uint(f);
    return (ushortT)((x + 0x7fffu + ((x >> 16) & 1u)) >> 16);
}

// ---- zero degi+fillc (contiguous 2N ints) ---------------------------------
__global__ void k_zero(uint4* __restrict__ p, int n4) {
    int i = blockIdx.x * blockDim.x + threadIdx.x;
    if (i < n4) p[i] = uint4{0, 0, 0, 0};
}

__global__ void k_deg(const int* __restrict__ col, int* __restrict__ degi, int E) {
    int e = blockIdx.x * blockDim.x + threadIdx.x;
    if (e < E) atomicAdd(&degi[col[e]], 1);
}

// ---- scan1 also produces invs ---------------------------------------------
__global__ void k_scan1(const int* __restrict__ degi, int* __restrict__ incl,
                        int* __restrict__ bsum, float* __restrict__ invs, int N) {
    __shared__ int s[256];
    int t = threadIdx.x;
    int i = blockIdx.x * 256 + t;
    int v = (i < N) ? degi[i] : 0;
    if (i < N) invs[i] = rsqrtf((float)v + 1.0f);
    s[t] = v;
    __syncthreads();
    for (int off = 1; off < 256; off <<= 1) {
        int u = (t >= off) ? s[t - off] : 0;
        __syncthreads();
        s[t] += u;
        __syncthreads();
    }
    if (i < N) incl[i] = s[t];
    if (t == 255) bsum[blockIdx.x] = s[255];
}

// ---- scan2 (single block) + zero pooling accumulators ---------------------
__global__ void k_scan2(const int* __restrict__ bsum, int* __restrict__ bofs,
                        float* __restrict__ sums, float* __restrict__ cnts,
                        int NB, int G) {
    __shared__ int s[256];
    int t = threadIdx.x;
    for (int i = t; i < 3 * G; i += 256) {
        if (i < 2 * G) sums[i] = 0.f;
        else cnts[i - 2 * G] = 0.f;
    }
    int v = (t < NB) ? bsum[t] : 0;
    s[t] = v;
    __syncthreads();
    for (int off = 1; off < 256; off <<= 1) {
        int u = (t >= off) ? s[t - off] : 0;
        __syncthreads();
        s[t] += u;
        __syncthreads();
    }
    if (t < NB) bofs[t] = s[t] - v;  // exclusive
}

__global__ void k_scan3(const int* __restrict__ degi, const int* __restrict__ bofs,
                        int* __restrict__ indptr, int N) {
    int i = blockIdx.x * 256 + threadIdx.x;
    if (i < N) {
        int incl = indptr[i];
        int base = bofs[blockIdx.x];
        indptr[i] = incl - degi[i] + base;
        if (i == N - 1) indptr[N] = incl + base;
    }
}

// ---- CSR fill: ONE packed 8B store per edge -------------------------------
__global__ void k_fill(const int* __restrict__ row, const int* __restrict__ col,
                       const int* __restrict__ indptr, int* __restrict__ fill,
                       const float* __restrict__ invs, uint2* __restrict__ epack,
                       int E) {
    int e = blockIdx.x * blockDim.x + threadIdx.x;
    if (e < E) {
        int r = row[e], c = col[e];
        int p = indptr[c] + atomicAdd(&fill[c], 1);
        uint2 pk;
        pk.x = (uintT)r;
        pk.y = __float_as_uint(invs[r] * invs[c]);
        epack[p] = pk;
    }
}

// ---- prep: weights fp32 -> transposed bf16 hi/lo, and X -> bf16 -----------
__global__ void k_prep(const float* __restrict__ X, ushortT* __restrict__ Xb,
                       const float* __restrict__ w0, const float* __restrict__ w1,
                       const float* __restrict__ w2, const float* __restrict__ w3,
                       ushortT* __restrict__ Whi, ushortT* __restrict__ Wlo,
                       int total4) {
    if (blockIdx.x < 256) {
        int idx = blockIdx.x * 256 + threadIdx.x;  // 0..65535
        int m = idx >> 14;
        int r = idx & 16383;
        int n = r >> 7;
        int k = r & 127;
        const float* W = (m == 0) ? w0 : (m == 1) ? w1 : (m == 2) ? w2 : w3;
        float w = W[k * CH + n];
        ushortT hi = f2bf(w);
        float lo = w - bf2f(hi);
        Whi[m * 16384 + n * CH + k] = hi;
        Wlo[m * 16384 + n * CH + k] = f2bf(lo);
    } else {
        int i = (blockIdx.x - 256) * 256 + threadIdx.x;
        if (i < total4) {
            float4 v = reinterpret_cast<const float4*>(X)[i];
            uint2 o;
            o.x = (uintT)f2bf(v.x) | ((uintT)f2bf(v.y) << 16);
            o.y = (uintT)f2bf(v.z) | ((uintT)f2bf(v.w) << 16);
            reinterpret_cast<uint2*>(Xb)[i] = o;
        }
    }
}

// ---- aggregation (bf16 in/out, fp32 accumulate, 8-wide gather) ------------
__global__ __launch_bounds__(256) void k_agg(const ushortT* __restrict__ Hb,
                                             const uint2* __restrict__ epack,
                                             const int* __restrict__ indptr,
                                             const float* __restrict__ invs,
                                             ushortT* __restrict__ Zb, int N) {
    int node = blockIdx.x * 4 + (threadIdx.x >> 6);
    if (node >= N) return;
    int lane = threadIdx.x & 63;

    const uintT* H32 = reinterpret_cast<const uintT*>(Hb);

    float sn = invs[node];
    float sn2 = sn * sn;
    uintT hu = H32[(size_t)node * 64 + lane];
    float ax = sn2 * bf2f(hu & 0xffffu);
    float ay = sn2 * bf2f(hu >> 16);

    int p = indptr[node];
    int p1 = indptr[node + 1];
    for (; p + 8 <= p1; p += 8) {
        uint2 e[8];
#pragma unroll
        for (int i = 0; i < 8; ++i) e[i] = epack[p + i];
        uintT g[8];
#pragma unroll
        for (int i = 0; i < 8; ++i) g[i] = H32[(size_t)(int)e[i].x * 64 + lane];
#pragma unroll
        for (int i = 0; i < 8; ++i) {
            float wv = __uint_as_float(e[i].y);
            ax += wv * bf2f(g[i] & 0xffffu);
            ay += wv * bf2f(g[i] >> 16);
        }
    }
    if (p + 4 <= p1) {
        uint2 e[4];
#pragma unroll
        for (int i = 0; i < 4; ++i) e[i] = epack[p + i];
        uintT g[4];
#pragma unroll
        for (int i = 0; i < 4; ++i) g[i] = H32[(size_t)(int)e[i].x * 64 + lane];
#pragma unroll
        for (int i = 0; i < 4; ++i) {
            float wv = __uint_as_float(e[i].y);
            ax += wv * bf2f(g[i] & 0xffffu);
            ay += wv * bf2f(g[i] >> 16);
        }
        p += 4;
    }
    for (; p < p1; ++p) {
        uint2 e = epack[p];
        uintT g = H32[(size_t)(int)e.x * 64 + lane];
        float wv = __uint_as_float(e.y);
        ax += wv * bf2f(g & 0xffffu);
        ay += wv * bf2f(g >> 16);
    }
    uintT o = (uintT)f2bf(ax) | ((uintT)f2bf(ay) << 16);
    reinterpret_cast<uintT*>(Zb)[(size_t)node * 64 + lane] = o;
}

// ---- MFMA GEMM: Out[N,128] = relu?(Z[N,128] @ (Whi+Wlo) + b), all bf16 ----
#define SA 40
#define SC 132
__global__ __launch_bounds__(256) void k_gemm(const ushortT* __restrict__ Zg,
                                              const ushortT* __restrict__ Whi,
                                              const ushortT* __restrict__ Wlo,
                                              const float* __restrict__ Bias,
                                              ushortT* __restrict__ Out, int N,
                                              int doRelu) {
    __shared__ ushortT As[128 * SA];
    __shared__ ushortT Hs[128 * SA];
    __shared__ ushortT Ls[128 * SA];
    __shared__ ushortT Cs[128 * SC];

    const int tid = threadIdx.x;
    const int wave = tid >> 6, lane = tid & 63;
    const int quad = lane >> 4, l15 = lane & 15;
    const int mBase = (wave >> 1) * 64, nBase = (wave & 1) * 64;
    const int row0 = blockIdx.x * 128;
    const int r = tid >> 1, half = tid & 1;

    floatx4 acc[4][4];
    const floatx4 zero4 = {0.f, 0.f, 0.f, 0.f};
#pragma unroll
    for (int i = 0; i < 4; i++)
#pragma unroll
        for (int j = 0; j < 4; j++) acc[i][j] = zero4;

    for (int ks = 0; ks < 4; ++ks) {
        {
            int grow = row0 + r;
            uint4 av0 = {0, 0, 0, 0}, av1 = {0, 0, 0, 0};
            if (grow < N) {
                const uint4* s = reinterpret_cast<const uint4*>(
                    Zg + (size_t)grow * CH + ks * 32 + half * 16);
                av0 = s[0]; av1 = s[1];
            }
            uint4* d = reinterpret_cast<uint4*>(&As[r * SA + half * 16]);
            d[0] = av0; d[1] = av1;
            const uint4* sh = reinterpret_cast<const uint4*>(Whi + r * CH + ks * 32 + half * 16);
            uint4* dh = reinterpret_cast<uint4*>(&Hs[r * SA + half * 16]);
            dh[0] = sh[0]; dh[1] = sh[1];
            const uint4* sl = reinterpret_cast<const uint4*>(Wlo + r * CH + ks * 32 + half * 16);
            uint4* dl = reinterpret_cast<uint4*>(&Ls[r * SA + half * 16]);
            dl[0] = sl[0]; dl[1] = sl[1];
        }
        __syncthreads();

        short8 af[4], hf[4], lf[4];
#pragma unroll
        for (int mt = 0; mt < 4; ++mt)
            af[mt] = *reinterpret_cast<const short8*>(&As[(mBase + mt * 16 + l15) * SA + quad * 8]);
#pragma unroll
        for (int nt = 0; nt < 4; ++nt) {
            hf[nt] = *reinterpret_cast<const short8*>(&Hs[(nBase + nt * 16 + l15) * SA + quad * 8]);
            lf[nt] = *reinterpret_cast<const short8*>(&Ls[(nBase + nt * 16 + l15) * SA + quad * 8]);
        }
#pragma unroll
        for (int mt = 0; mt < 4; ++mt)
#pragma unroll
            for (int nt = 0; nt < 4; ++nt) {
                acc[mt][nt] = __builtin_amdgcn_mfma_f32_16x16x32_bf16(af[mt], hf[nt], acc[mt][nt], 0, 0, 0);
                acc[mt][nt] = __builtin_amdgcn_mfma_f32_16x16x32_bf16(af[mt], lf[nt], acc[mt][nt], 0, 0, 0);
            }
        __syncthreads();
    }

    float bb[4];
#pragma unroll
    for (int nt = 0; nt < 4; ++nt) bb[nt] = Bias[nBase + nt * 16 + l15];

#pragma unroll
    for (int mt = 0; mt < 4; ++mt)
#pragma unroll
        for (int nt = 0; nt < 4; ++nt)
#pragma unroll
            for (int r4 = 0; r4 < 4; ++r4) {
                int lrow = mBase + mt * 16 + quad * 4 + r4;
                float v = acc[mt][nt][r4] + bb[nt];
                if (doRelu) v = fmaxf(v, 0.f);
                Cs[lrow * SC + nBase + nt * 16 + l15] = f2bf(v);
            }
    __syncthreads();
    {
        int grow = row0 + r;
        if (grow < N) {
            const uint2* s = reinterpret_cast<const uint2*>(&Cs[r * SC + half * 64]);
            uint4* dst = reinterpret_cast<uint4*>(Out + (size_t)grow * CH + half * 64);
#pragma unroll
            for (int q = 0; q < 8; ++q) {
                uint2 a = s[2 * q], b = s[2 * q + 1];
                uint4 o = {a.x, a.y, b.x, b.y};
                dst[q] = o;
            }
        }
    }
}

// ---- fused FC2 + mean-pool accumulation -----------------------------------
// 32 nodes/block (4 waves x 8 nodes); LDS per-graph partial sums then
// global atomics only for graphs present in the block.
__global__ __launch_bounds__(256) void k_fc2pool(const ushortT* __restrict__ H,
                                                 const float* __restrict__ W2,
                                                 const float* __restrict__ B2,
                                                 const int* __restrict__ batch,
                                                 float* __restrict__ sums,
                                                 float* __restrict__ cnts, int N) {
    __shared__ float ls[192];  // [0..63]=sum0 [64..127]=sum1 [128..191]=cnt
    int t = threadIdx.x;
    if (t < 192) ls[t] = 0.f;
    __syncthreads();
    int wave = t >> 6, lane = t & 63;
    float4 w = *reinterpret_cast<const float4*>(W2 + lane * 4);
    float b0 = B2[0], b1 = B2[1];
    int base = blockIdx.x * 32 + wave * 8;
    for (int i = 0; i < 8; ++i) {
        int node = base + i;
        if (node >= N) break;
        uintT hu = reinterpret_cast<const uintT*>(H)[(size_t)node * 64 + lane];
        float hx = bf2f(hu & 0xffffu), hy = bf2f(hu >> 16);
        float d0 = hx * w.x + hy * w.z;
        float d1 = hx * w.y + hy * w.w;
#pragma unroll
        for (int off = 32; off > 0; off >>= 1) {
            d0 += __shfl_down(d0, off, 64);
            d1 += __shfl_down(d1, off, 64);
        }
        if (lane == 0) {
            int g = batch[node];
            atomicAdd(&ls[g], d0 + b0);
            atomicAdd(&ls[64 + g], d1 + b1);
            atomicAdd(&ls[128 + g], 1.0f);
        }
    }
    __syncthreads();
    if (t < 64) {
        float c = ls[128 + t];
        if (c != 0.f) {
            atomicAdd(&sums[2 * t], ls[t]);
            atomicAdd(&sums[2 * t + 1], ls[64 + t]);
            atomicAdd(&cnts[t], c);
        }
    }
}

__global__ void k_softmax(const float* __restrict__ sums, const float* __restrict__ cnts,
                          float* __restrict__ out, int G) {
    int g = blockIdx.x * blockDim.x + threadIdx.x;
    if (g < G) {
        float c = fmaxf(cnts[g], 1.0f);
        float p0 = sums[2 * g] / c;
        float p1 = sums[2 * g + 1] / c;
        float m = fmaxf(p0, p1);
        float e0 = expf(p0 - m), e1 = expf(p1 - m);
        float inv = 1.f / (e0 + e1);
        out[2 * g] = e0 * inv;
        out[2 * g + 1] = e1 * inv;
    }
}

// ---------------------------------------------------------------------------
extern "C" void kernel_launch(void* const* d_in, const int* in_sizes, int n_in,
                              void* d_out, int out_size, void* d_ws, size_t ws_size,
                              hipStream_t stream) {
    const float* X   = (const float*)d_in[0];
    const int* EI    = (const int*)d_in[1];
    const int* BATCH = (const int*)d_in[2];
    const float* W1  = (const float*)d_in[3];
    const float* B1  = (const float*)d_in[4];
    const float* W2  = (const float*)d_in[5];
    const float* B2  = (const float*)d_in[6];
    const float* W3  = (const float*)d_in[7];
    const float* B3  = (const float*)d_in[8];
    const float* FW1 = (const float*)d_in[9];
    const float* FB1 = (const float*)d_in[10];
    const float* FW2 = (const float*)d_in[11];
    const float* FB2 = (const float*)d_in[12];

    const int N = in_sizes[0] / CH;
    const int E = in_sizes[1] / 2;
    const int G = out_size / 2;
    const int* rowp = EI;
    const int* colp = EI + E;

    char* w = (char*)d_ws;
    auto alloc = [&](size_t bytes) -> char* {
        char* p = w;
        w += (bytes + 255) & ~(size_t)255;
        return p;
    };
    ushortT* Hb    = (ushortT*)alloc((size_t)N * CH * 2);
    ushortT* Zb    = (ushortT*)alloc((size_t)N * CH * 2);
    ushortT* Xb    = (ushortT*)alloc((size_t)N * CH * 2);
    ushortT* WhiA  = (ushortT*)alloc((size_t)4 * 16384 * 2);
    ushortT* WloA  = (ushortT*)alloc((size_t)4 * 16384 * 2);
    int*   degi    = (int*)alloc((size_t)2 * N * 4);  // degi | fillc contiguous
    int*   fillc   = degi + N;
    float* invs    = (float*)alloc((size_t)N * 4);
    int*   indptr  = (int*)alloc((size_t)(N + 1) * 4);
    uint2* epack   = (uint2*)alloc((size_t)E * 8);
    int*   bsum    = (int*)alloc(1024 * 4);
    int*   bofs    = (int*)alloc(1024 * 4);
    float* sums    = (float*)alloc((size_t)G * 2 * 4);
    float* cnts    = (float*)alloc((size_t)G * 4);

    const int nb256  = (N + 255) / 256;
    const int nbE    = (E + 255) / 256;
    const int nbAgg  = (N + 3) / 4;
    const int nbGemm = (N + 127) / 128;
    const int total4 = N * CH / 4;

    k_zero<<<(2 * N / 4 + 255) / 256, 256, 0, stream>>>((uint4*)degi, 2 * N / 4);
    k_deg<<<nbE, 256, 0, stream>>>(colp, degi, E);
    k_scan1<<<nb256, 256, 0, stream>>>(degi, indptr, bsum, invs, N);
    k_scan2<<<1, 256, 0, stream>>>(bsum, bofs, sums, cnts, nb256, G);
    k_scan3<<<nb256, 256, 0, stream>>>(degi, bofs, indptr, N);
    k_fill<<<nbE, 256, 0, stream>>>(rowp, colp, indptr, fillc, invs, epack, E);
    k_prep<<<256 + (total4 + 255) / 256, 256, 0, stream>>>(X, Xb, W1, W2, W3, FW1,
                                                           WhiA, WloA, total4);

    // layer 1
    k_agg<<<nbAgg, 256, 0, stream>>>(Xb, epack, indptr, invs, Zb, N);
    k_gemm<<<nbGemm, 256, 0, stream>>>(Zb, WhiA, WloA, B1, Hb, N, 1);
    // layer 2
    k_agg<<<nbAgg, 256, 0, stream>>>(Hb, epack, indptr, invs, Zb, N);
    k_gemm<<<nbGemm, 256, 0, stream>>>(Zb, WhiA + 16384, WloA + 16384, B2, Hb, N, 1);
    // layer 3
    k_agg<<<nbAgg, 256, 0, stream>>>(Hb, epack, indptr, invs, Zb, N);
    k_gemm<<<nbGemm, 256, 0, stream>>>(Zb, WhiA + 2 * 16384, WloA + 2 * 16384, B3, Hb, N, 1);
    // FC1
    k_gemm<<<nbGemm, 256, 0, stream>>>(Hb, WhiA + 3 * 16384, WloA + 3 * 16384, FB1, Zb, N, 1);
    // FC2 + pool + softmax
    k_fc2pool<<<(N + 31) / 32, 256, 0, stream>>>(Zb, FW2, FB2, BATCH, sums, cnts, N);
    k_softmax<<<(G + 63) / 64, 64, 0, stream>>>(sums, cnts, (float*)d_out, G);
}

// Round 5
// 310.781 us; speedup vs baseline: 1.6387x; 1.1528x over previous
//
#include <hip/hip_runtime.h>

// ---------------------------------------------------------------------------
// colorableGNN: 3x GCN(128->128) + FC(128->128) + FC(128->2) + mean-pool + softmax
// R4: replace k_deg + k_fill (global atomics + 8B random scatter -> 53MB
// writeback, 43us) with a bucketed counting sort: bin edges into 128-dst
// buckets with LDS staging (coalesced segment writes), per-bucket LDS
// histogram for degrees (no global atomics), per-bucket LDS scatter with
// contiguous streamed output. Activations bf16, GEMM = MFMA hi/lo split.
// ---------------------------------------------------------------------------

#define CH 128
#define BSH 7              // 128 dst nodes per bucket
#define SEG 4096           // segment capacity (records) per bucket
#define EPW 4096           // edges per phase-1 workgroup

typedef unsigned short ushortT;
typedef unsigned int uintT;
typedef __attribute__((ext_vector_type(8))) short short8;
typedef __attribute__((ext_vector_type(4))) float floatx4;

__device__ __forceinline__ float bf2f(uintT u) {
    return __uint_as_float(u << 16);
}
__device__ __forceinline__ ushortT f2bf(float f) {
    uintT x = __float_as_uint(f);
    return (ushortT)((x + 0x7fffu + ((x >> 16) & 1u)) >> 16);
}

// ---- zero bucket fill counters --------------------------------------------
__global__ void k_zero(int* __restrict__ bfill, int NB) {
    int i = blockIdx.x * blockDim.x + threadIdx.x;
    if (i < NB) bfill[i] = 0;
}

// ---- phase 1: bin edges into dst-buckets, LDS-staged coalesced writes -----
__global__ __launch_bounds__(256) void k_bin(const int* __restrict__ row,
                                             const int* __restrict__ col,
                                             int* __restrict__ bfill,
                                             uint2* __restrict__ seg,
                                             int E, int NB) {
    __shared__ uint2 staged[EPW];   // 32 KB
    __shared__ int target[EPW];     // 16 KB
    __shared__ int sval[512];       // scan array (inclusive)
    __shared__ int horig[512];
    __shared__ int pcnt[512];
    __shared__ int gbase[512];
    const int t = threadIdx.x;
    const int e0 = blockIdx.x * EPW;
    const int cnt = min(EPW, E - e0);

    sval[t] = 0; sval[t + 256] = 0;
    __syncthreads();

    int er[16], ec[16];
#pragma unroll
    for (int i = 0; i < 16; ++i) {
        int le = i * 256 + t;
        if (le < cnt) {
            er[i] = row[e0 + le];
            ec[i] = col[e0 + le];
            atomicAdd(&sval[ec[i] >> BSH], 1);
        }
    }
    __syncthreads();
    horig[t] = sval[t]; horig[t + 256] = sval[t + 256];
    __syncthreads();
    // Hillis-Steele inclusive scan over 512 entries (read-all, sync, write-all)
    for (int off = 1; off < 512; off <<= 1) {
        int a = (t >= off) ? sval[t - off] : 0;
        int b2 = sval[t + 256 - off];
        __syncthreads();
        sval[t] += a;
        sval[t + 256] += b2;
        __syncthreads();
    }
    // reserve global segment space; init placement counters to local offsets
    for (int b = t; b < 512; b += 256) {
        int h = horig[b];
        pcnt[b] = sval[b] - h;  // exclusive local offset
        gbase[b] = (h > 0 && b < NB) ? atomicAdd(&bfill[b], h) : 0;
    }
    __syncthreads();
#pragma unroll
    for (int i = 0; i < 16; ++i) {
        int le = i * 256 + t;
        if (le < cnt) {
            int b = ec[i] >> BSH;
            int j = atomicAdd(&pcnt[b], 1);
            staged[j] = uint2{(uintT)er[i], (uintT)ec[i]};
            int lo = sval[b] - horig[b];
            target[j] = b * SEG + gbase[b] + (j - lo);
        }
    }
    __syncthreads();
    for (int s = t; s < cnt; s += 256) {
        int tg = target[s];
        seg[tg] = staged[s];  // mostly-contiguous runs per bucket group
    }
}

// ---- phase 2a: per-bucket degree histogram (replaces global-atomic k_deg) -
__global__ __launch_bounds__(256) void k_bdeg(const int* __restrict__ bfill,
                                              const uint2* __restrict__ seg,
                                              int* __restrict__ degi, int N) {
    __shared__ int h[128];
    const int b = blockIdx.x;
    const int t = threadIdx.x;
    if (t < 128) h[t] = 0;
    __syncthreads();
    int cnt = bfill[b];
    const uint2* sp = seg + (size_t)b * SEG;
    for (int s = t; s < cnt; s += 256) atomicAdd(&h[sp[s].y & 127], 1);
    __syncthreads();
    int d = b * 128 + t;
    if (t < 128 && d < N) degi[d] = h[t];
}

// ---- scan1 also produces invs ---------------------------------------------
__global__ void k_scan1(const int* __restrict__ degi, int* __restrict__ incl,
                        int* __restrict__ bsum, float* __restrict__ invs, int N) {
    __shared__ int s[256];
    int t = threadIdx.x;
    int i = blockIdx.x * 256 + t;
    int v = (i < N) ? degi[i] : 0;
    if (i < N) invs[i] = rsqrtf((float)v + 1.0f);
    s[t] = v;
    __syncthreads();
    for (int off = 1; off < 256; off <<= 1) {
        int u = (t >= off) ? s[t - off] : 0;
        __syncthreads();
        s[t] += u;
        __syncthreads();
    }
    if (i < N) incl[i] = s[t];
    if (t == 255) bsum[blockIdx.x] = s[255];
}

// ---- scan2 (single block) + zero pooling accumulators ---------------------
__global__ void k_scan2(const int* __restrict__ bsum, int* __restrict__ bofs,
                        float* __restrict__ sums, float* __restrict__ cnts,
                        int NB, int G) {
    __shared__ int s[256];
    int t = threadIdx.x;
    for (int i = t; i < 3 * G; i += 256) {
        if (i < 2 * G) sums[i] = 0.f;
        else cnts[i - 2 * G] = 0.f;
    }
    int v = (t < NB) ? bsum[t] : 0;
    s[t] = v;
    __syncthreads();
    for (int off = 1; off < 256; off <<= 1) {
        int u = (t >= off) ? s[t - off] : 0;
        __syncthreads();
        s[t] += u;
        __syncthreads();
    }
    if (t < NB) bofs[t] = s[t] - v;  // exclusive
}

__global__ void k_scan3(const int* __restrict__ degi, const int* __restrict__ bofs,
                        int* __restrict__ indptr, int N) {
    int i = blockIdx.x * 256 + threadIdx.x;
    if (i < N) {
        int incl = indptr[i];
        int base = bofs[blockIdx.x];
        indptr[i] = incl - degi[i] + base;
        if (i == N - 1) indptr[N] = incl + base;
    }
}

// ---- phase 2b: per-bucket CSR scatter, LDS-staged, contiguous output ------
__global__ __launch_bounds__(256) void k_scatter(const int* __restrict__ bfill,
                                                 const uint2* __restrict__ seg,
                                                 const int* __restrict__ indptr,
                                                 const float* __restrict__ invs,
                                                 uint2* __restrict__ epack, int N) {
    __shared__ uint2 staged[SEG];   // 32 KB
    __shared__ int loff[129];
    __shared__ int pc[128];
    const int b = blockIdx.x;
    const int t = threadIdx.x;
    const int d0 = b * 128;
    if (t < 129) {
        int d = d0 + t;
        if (d > N) d = N;
        loff[t] = indptr[d];
    }
    __syncthreads();
    int base = loff[0];
    if (t < 128) pc[t] = loff[t] - base;
    __syncthreads();
    int cnt = bfill[b];
    const uint2* sp = seg + (size_t)b * SEG;
    if (cnt <= SEG) {
        for (int s = t; s < cnt; s += 256) {
            uint2 rc = sp[s];
            int src = (int)rc.x, dst = (int)rc.y;
            int j = atomicAdd(&pc[dst & 127], 1);
            uint2 pk;
            pk.x = rc.x;
            pk.y = __float_as_uint(invs[src] * invs[dst]);
            staged[j] = pk;
        }
        __syncthreads();
        int tot = loff[128] - base;
        for (int s = t; s < tot; s += 256) epack[base + s] = staged[s];
    } else {  // pathological fallback (never for this dataset)
        for (int s = t; s < cnt; s += 256) {
            uint2 rc = sp[s];
            int src = (int)rc.x, dst = (int)rc.y;
            int j = atomicAdd(&pc[dst & 127], 1);
            uint2 pk;
            pk.x = rc.x;
            pk.y = __float_as_uint(invs[src] * invs[dst]);
            epack[base + j] = pk;
        }
    }
}

// ---- prep: weights fp32 -> transposed bf16 hi/lo, and X -> bf16 -----------
__global__ void k_prep(const float* __restrict__ X, ushortT* __restrict__ Xb,
                       const float* __restrict__ w0, const float* __restrict__ w1,
                       const float* __restrict__ w2, const float* __restrict__ w3,
                       ushortT* __restrict__ Whi, ushortT* __restrict__ Wlo,
                       int total4) {
    if (blockIdx.x < 256) {
        int idx = blockIdx.x * 256 + threadIdx.x;  // 0..65535
        int m = idx >> 14;
        int r = idx & 16383;
        int n = r >> 7;
        int k = r & 127;
        const float* W = (m == 0) ? w0 : (m == 1) ? w1 : (m == 2) ? w2 : w3;
        float w = W[k * CH + n];
        ushortT hi = f2bf(w);
        float lo = w - bf2f(hi);
        Whi[m * 16384 + n * CH + k] = hi;
        Wlo[m * 16384 + n * CH + k] = f2bf(lo);
    } else {
        int i = (blockIdx.x - 256) * 256 + threadIdx.x;
        if (i < total4) {
            float4 v = reinterpret_cast<const float4*>(X)[i];
            uint2 o;
            o.x = (uintT)f2bf(v.x) | ((uintT)f2bf(v.y) << 16);
            o.y = (uintT)f2bf(v.z) | ((uintT)f2bf(v.w) << 16);
            reinterpret_cast<uint2*>(Xb)[i] = o;
        }
    }
}

// ---- aggregation (bf16 in/out, fp32 accumulate, 8-wide gather) ------------
__global__ __launch_bounds__(256) void k_agg(const ushortT* __restrict__ Hb,
                                             const uint2* __restrict__ epack,
                                             const int* __restrict__ indptr,
                                             const float* __restrict__ invs,
                                             ushortT* __restrict__ Zb, int N) {
    int node = blockIdx.x * 4 + (threadIdx.x >> 6);
    if (node >= N) return;
    int lane = threadIdx.x & 63;

    const uintT* H32 = reinterpret_cast<const uintT*>(Hb);

    float sn = invs[node];
    float sn2 = sn * sn;
    uintT hu = H32[(size_t)node * 64 + lane];
    float ax = sn2 * bf2f(hu & 0xffffu);
    float ay = sn2 * bf2f(hu >> 16);

    int p = indptr[node];
    int p1 = indptr[node + 1];
    for (; p + 8 <= p1; p += 8) {
        uint2 e[8];
#pragma unroll
        for (int i = 0; i < 8; ++i) e[i] = epack[p + i];
        uintT g[8];
#pragma unroll
        for (int i = 0; i < 8; ++i) g[i] = H32[(size_t)(int)e[i].x * 64 + lane];
#pragma unroll
        for (int i = 0; i < 8; ++i) {
            float wv = __uint_as_float(e[i].y);
            ax += wv * bf2f(g[i] & 0xffffu);
            ay += wv * bf2f(g[i] >> 16);
        }
    }
    if (p + 4 <= p1) {
        uint2 e[4];
#pragma unroll
        for (int i = 0; i < 4; ++i) e[i] = epack[p + i];
        uintT g[4];
#pragma unroll
        for (int i = 0; i < 4; ++i) g[i] = H32[(size_t)(int)e[i].x * 64 + lane];
#pragma unroll
        for (int i = 0; i < 4; ++i) {
            float wv = __uint_as_float(e[i].y);
            ax += wv * bf2f(g[i] & 0xffffu);
            ay += wv * bf2f(g[i] >> 16);
        }
        p += 4;
    }
    for (; p < p1; ++p) {
        uint2 e = epack[p];
        uintT g = H32[(size_t)(int)e.x * 64 + lane];
        float wv = __uint_as_float(e.y);
        ax += wv * bf2f(g & 0xffffu);
        ay += wv * bf2f(g >> 16);
    }
    uintT o = (uintT)f2bf(ax) | ((uintT)f2bf(ay) << 16);
    reinterpret_cast<uintT*>(Zb)[(size_t)node * 64 + lane] = o;
}

// ---- MFMA GEMM: Out[N,128] = relu?(Z[N,128] @ (Whi+Wlo) + b), all bf16 ----
#define SA 40
#define SC 132
__global__ __launch_bounds__(256) void k_gemm(const ushortT* __restrict__ Zg,
                                              const ushortT* __restrict__ Whi,
                                              const ushortT* __restrict__ Wlo,
                                              const float* __restrict__ Bias,
                                              ushortT* __restrict__ Out, int N,
                                              int doRelu) {
    __shared__ ushortT As[128 * SA];
    __shared__ ushortT Hs[128 * SA];
    __shared__ ushortT Ls[128 * SA];
    __shared__ ushortT Cs[128 * SC];

    const int tid = threadIdx.x;
    const int wave = tid >> 6, lane = tid & 63;
    const int quad = lane >> 4, l15 = lane & 15;
    const int mBase = (wave >> 1) * 64, nBase = (wave & 1) * 64;
    const int row0 = blockIdx.x * 128;
    const int r = tid >> 1, half = tid & 1;

    floatx4 acc[4][4];
    const floatx4 zero4 = {0.f, 0.f, 0.f, 0.f};
#pragma unroll
    for (int i = 0; i < 4; i++)
#pragma unroll
        for (int j = 0; j < 4; j++) acc[i][j] = zero4;

    for (int ks = 0; ks < 4; ++ks) {
        {
            int grow = row0 + r;
            uint4 av0 = {0, 0, 0, 0}, av1 = {0, 0, 0, 0};
            if (grow < N) {
                const uint4* s = reinterpret_cast<const uint4*>(
                    Zg + (size_t)grow * CH + ks * 32 + half * 16);
                av0 = s[0]; av1 = s[1];
            }
            uint4* d = reinterpret_cast<uint4*>(&As[r * SA + half * 16]);
            d[0] = av0; d[1] = av1;
            const uint4* sh = reinterpret_cast<const uint4*>(Whi + r * CH + ks * 32 + half * 16);
            uint4* dh = reinterpret_cast<uint4*>(&Hs[r * SA + half * 16]);
            dh[0] = sh[0]; dh[1] = sh[1];
            const uint4* sl = reinterpret_cast<const uint4*>(Wlo + r * CH + ks * 32 + half * 16);
            uint4* dl = reinterpret_cast<uint4*>(&Ls[r * SA + half * 16]);
            dl[0] = sl[0]; dl[1] = sl[1];
        }
        __syncthreads();

        short8 af[4], hf[4], lf[4];
#pragma unroll
        for (int mt = 0; mt < 4; ++mt)
            af[mt] = *reinterpret_cast<const short8*>(&As[(mBase + mt * 16 + l15) * SA + quad * 8]);
#pragma unroll
        for (int nt = 0; nt < 4; ++nt) {
            hf[nt] = *reinterpret_cast<const short8*>(&Hs[(nBase + nt * 16 + l15) * SA + quad * 8]);
            lf[nt] = *reinterpret_cast<const short8*>(&Ls[(nBase + nt * 16 + l15) * SA + quad * 8]);
        }
#pragma unroll
        for (int mt = 0; mt < 4; ++mt)
#pragma unroll
            for (int nt = 0; nt < 4; ++nt) {
                acc[mt][nt] = __builtin_amdgcn_mfma_f32_16x16x32_bf16(af[mt], hf[nt], acc[mt][nt], 0, 0, 0);
                acc[mt][nt] = __builtin_amdgcn_mfma_f32_16x16x32_bf16(af[mt], lf[nt], acc[mt][nt], 0, 0, 0);
            }
        __syncthreads();
    }

    float bb[4];
#pragma unroll
    for (int nt = 0; nt < 4; ++nt) bb[nt] = Bias[nBase + nt * 16 + l15];

#pragma unroll
    for (int mt = 0; mt < 4; ++mt)
#pragma unroll
        for (int nt = 0; nt < 4; ++nt)
#pragma unroll
            for (int r4 = 0; r4 < 4; ++r4) {
                int lrow = mBase + mt * 16 + quad * 4 + r4;
                float v = acc[mt][nt][r4] + bb[nt];
                if (doRelu) v = fmaxf(v, 0.f);
                Cs[lrow * SC + nBase + nt * 16 + l15] = f2bf(v);
            }
    __syncthreads();
    {
        int grow = row0 + r;
        if (grow < N) {
            const uint2* s = reinterpret_cast<const uint2*>(&Cs[r * SC + half * 64]);
            uint4* dst = reinterpret_cast<uint4*>(Out + (size_t)grow * CH + half * 64);
#pragma unroll
            for (int q = 0; q < 8; ++q) {
                uint2 a = s[2 * q], b = s[2 * q + 1];
                uint4 o = {a.x, a.y, b.x, b.y};
                dst[q] = o;
            }
        }
    }
}

// ---- fused FC2 + mean-pool accumulation -----------------------------------
__global__ __launch_bounds__(256) void k_fc2pool(const ushortT* __restrict__ H,
                                                 const float* __restrict__ W2,
                                                 const float* __restrict__ B2,
                                                 const int* __restrict__ batch,
                                                 float* __restrict__ sums,
                                                 float* __restrict__ cnts, int N) {
    __shared__ float ls[192];
    int t = threadIdx.x;
    if (t < 192) ls[t] = 0.f;
    __syncthreads();
    int wave = t >> 6, lane = t & 63;
    float4 w = *reinterpret_cast<const float4*>(W2 + lane * 4);
    float b0 = B2[0], b1 = B2[1];
    int base = blockIdx.x * 32 + wave * 8;
    for (int i = 0; i < 8; ++i) {
        int node = base + i;
        if (node >= N) break;
        uintT hu = reinterpret_cast<const uintT*>(H)[(size_t)node * 64 + lane];
        float hx = bf2f(hu & 0xffffu), hy = bf2f(hu >> 16);
        float d0 = hx * w.x + hy * w.z;
        float d1 = hx * w.y + hy * w.w;
#pragma unroll
        for (int off = 32; off > 0; off >>= 1) {
            d0 += __shfl_down(d0, off, 64);
            d1 += __shfl_down(d1, off, 64);
        }
        if (lane == 0) {
            int g = batch[node];
            atomicAdd(&ls[g], d0 + b0);
            atomicAdd(&ls[64 + g], d1 + b1);
            atomicAdd(&ls[128 + g], 1.0f);
        }
    }
    __syncthreads();
    if (t < 64) {
        float c = ls[128 + t];
        if (c != 0.f) {
            atomicAdd(&sums[2 * t], ls[t]);
            atomicAdd(&sums[2 * t + 1], ls[64 + t]);
            atomicAdd(&cnts[t], c);
        }
    }
}

__global__ void k_softmax(const float* __restrict__ sums, const float* __restrict__ cnts,
                          float* __restrict__ out, int G) {
    int g = blockIdx.x * blockDim.x + threadIdx.x;
    if (g < G) {
        float c = fmaxf(cnts[g], 1.0f);
        float p0 = sums[2 * g] / c;
        float p1 = sums[2 * g + 1] / c;
        float m = fmaxf(p0, p1);
        float e0 = expf(p0 - m), e1 = expf(p1 - m);
        float inv = 1.f / (e0 + e1);
        out[2 * g] = e0 * inv;
        out[2 * g + 1] = e1 * inv;
    }
}

// ---------------------------------------------------------------------------
extern "C" void kernel_launch(void* const* d_in, const int* in_sizes, int n_in,
                              void* d_out, int out_size, void* d_ws, size_t ws_size,
                              hipStream_t stream) {
    const float* X   = (const float*)d_in[0];
    const int* EI    = (const int*)d_in[1];
    const int* BATCH = (const int*)d_in[2];
    const float* W1  = (const float*)d_in[3];
    const float* B1  = (const float*)d_in[4];
    const float* W2  = (const float*)d_in[5];
    const float* B2  = (const float*)d_in[6];
    const float* W3  = (const float*)d_in[7];
    const float* B3  = (const float*)d_in[8];
    const float* FW1 = (const float*)d_in[9];
    const float* FB1 = (const float*)d_in[10];
    const float* FW2 = (const float*)d_in[11];
    const float* FB2 = (const float*)d_in[12];

    const int N = in_sizes[0] / CH;
    const int E = in_sizes[1] / 2;
    const int G = out_size / 2;
    const int* rowp = EI;
    const int* colp = EI + E;
    const int NB = (N + 127) >> BSH;  // dst buckets of 128

    char* w = (char*)d_ws;
    auto alloc = [&](size_t bytes) -> char* {
        char* p = w;
        w += (bytes + 255) & ~(size_t)255;
        return p;
    };
    ushortT* Hb    = (ushortT*)alloc((size_t)N * CH * 2);
    ushortT* Zb    = (ushortT*)alloc((size_t)N * CH * 2);
    ushortT* Xb    = (ushortT*)alloc((size_t)N * CH * 2);
    ushortT* WhiA  = (ushortT*)alloc((size_t)4 * 16384 * 2);
    ushortT* WloA  = (ushortT*)alloc((size_t)4 * 16384 * 2);
    int*   degi    = (int*)alloc((size_t)N * 4);
    float* invs    = (float*)alloc((size_t)N * 4);
    int*   indptr  = (int*)alloc((size_t)(N + 1) * 4);
    uint2* epack   = (uint2*)alloc((size_t)E * 8);
    uint2* seg     = (uint2*)alloc((size_t)NB * SEG * 8);
    int*   bfill   = (int*)alloc((size_t)NB * 4);
    int*   bsum    = (int*)alloc(1024 * 4);
    int*   bofs    = (int*)alloc(1024 * 4);
    float* sums    = (float*)alloc((size_t)G * 2 * 4);
    float* cnts    = (float*)alloc((size_t)G * 4);

    const int nb256  = (N + 255) / 256;
    const int nbAgg  = (N + 3) / 4;
    const int nbGemm = (N + 127) / 128;
    const int nbBin  = (E + EPW - 1) / EPW;
    const int total4 = N * CH / 4;

    k_zero<<<(NB + 255) / 256, 256, 0, stream>>>(bfill, NB);
    k_bin<<<nbBin, 256, 0, stream>>>(rowp, colp, bfill, seg, E, NB);
    k_bdeg<<<NB, 256, 0, stream>>>(bfill, seg, degi, N);
    k_scan1<<<nb256, 256, 0, stream>>>(degi, indptr, bsum, invs, N);
    k_scan2<<<1, 256, 0, stream>>>(bsum, bofs, sums, cnts, nb256, G);
    k_scan3<<<nb256, 256, 0, stream>>>(degi, bofs, indptr, N);
    k_scatter<<<NB, 256, 0, stream>>>(bfill, seg, indptr, invs, epack, N);
    k_prep<<<256 + (total4 + 255) / 256, 256, 0, stream>>>(X, Xb, W1, W2, W3, FW1,
                                                           WhiA, WloA, total4);

    // layer 1
    k_agg<<<nbAgg, 256, 0, stream>>>(Xb, epack, indptr, invs, Zb, N);
    k_gemm<<<nbGemm, 256, 0, stream>>>(Zb, WhiA, WloA, B1, Hb, N, 1);
    // layer 2
    k_agg<<<nbAgg, 256, 0, stream>>>(Hb, epack, indptr, invs, Zb, N);
    k_gemm<<<nbGemm, 256, 0, stream>>>(Zb, WhiA + 16384, WloA + 16384, B2, Hb, N, 1);
    // layer 3
    k_agg<<<nbAgg, 256, 0, stream>>>(Hb, epack, indptr, invs, Zb, N);
    k_gemm<<<nbGemm, 256, 0, stream>>>(Zb, WhiA + 2 * 16384, WloA + 2 * 16384, B3, Hb, N, 1);
    // FC1
    k_gemm<<<nbGemm, 256, 0, stream>>>(Hb, WhiA + 3 * 16384, WloA + 3 * 16384, FB1, Zb, N, 1);
    // FC2 + pool + softmax
    k_fc2pool<<<(N + 31) / 32, 256, 0, stream>>>(Zb, FW2, FB2, BATCH, sums, cnts, N);
    k_softmax<<<(G + 63) / 64, 64, 0, stream>>>(sums, cnts, (float*)d_out, G);
}